// Round 3
// baseline (747.490 us; speedup 1.0000x reference)
//
#include <hip/hip_runtime.h>
#include <hip/hip_bf16.h>
#include <math.h>

#define N_NODES 50000
#define N_EDGES 1600000
#define DIM 128
#define EPS 1e-5f
#define SLOPE 0.2f
#define NB_SCAN 196   // ceil(50000/256)

#define NB 128        // dst buckets for partition
#define BDEPTH 64     // LDS entries per bucket
#define FLUSH 32      // flush chunk (32 * 8B = 256B)
#define EPB 3072      // edges per block in pass B
#define NBLK_B ((N_EDGES + EPB - 1) / EPB)

__device__ __forceinline__ float lrelu(float x) { return x > 0.f ? x : SLOPE * x; }

__device__ __forceinline__ unsigned short f2bf(float f) {
    unsigned u = __float_as_uint(f);
    unsigned r = (u + 0x7fffu + ((u >> 16) & 1u)) >> 16;
    return (unsigned short)r;
}

__device__ __forceinline__ float2 ldh2(const unsigned short* p) {
    unsigned u = *(const unsigned*)p;
    float2 r;
    r.x = __uint_as_float(u << 16);
    r.y = __uint_as_float(u & 0xffff0000u);
    return r;
}

__device__ __forceinline__ int bucket_of(int d) {
    return (int)(((long long)d * NB) / N_NODES);
}
__device__ __forceinline__ int dstart(int b) {
    return (int)(((long long)b * N_NODES + NB - 1) / NB);
}

// ---------------- CSR build ----------------
__global__ void k_degree(const int* __restrict__ dst, int* __restrict__ deg) {
    int i = blockIdx.x * blockDim.x + threadIdx.x;
    if (i < N_EDGES / 4) {
        int4 d = ((const int4*)dst)[i];
        atomicAdd(&deg[d.x], 1);
        atomicAdd(&deg[d.y], 1);
        atomicAdd(&deg[d.z], 1);
        atomicAdd(&deg[d.w], 1);
    }
}

__global__ void k_scan1(const int* __restrict__ deg, int* __restrict__ partial,
                        int* __restrict__ bsum) {
    __shared__ int s[256];
    int t = threadIdx.x, g = blockIdx.x * 256 + t;
    int v = (g < N_NODES) ? deg[g] : 0;
    s[t] = v;
    __syncthreads();
    for (int off = 1; off < 256; off <<= 1) {
        int x = s[t];
        int y = (t >= off) ? s[t - off] : 0;
        __syncthreads();
        s[t] = x + y;
        __syncthreads();
    }
    if (g < N_NODES) partial[g] = s[t] - v;
    if (t == 255) bsum[blockIdx.x] = s[255];
}

__global__ void k_scan2(const int* __restrict__ bsum, int* __restrict__ boff) {
    __shared__ int s[256];
    int t = threadIdx.x;
    int v = (t < NB_SCAN) ? bsum[t] : 0;
    s[t] = v;
    __syncthreads();
    for (int off = 1; off < 256; off <<= 1) {
        int x = s[t];
        int y = (t >= off) ? s[t - off] : 0;
        __syncthreads();
        s[t] = x + y;
        __syncthreads();
    }
    if (t < NB_SCAN) boff[t] = s[t] - v;
    if (t == 255) boff[NB_SCAN] = s[255];
}

__global__ void k_scan3(const int* __restrict__ partial, const int* __restrict__ boff,
                        int* __restrict__ row_ptr) {
    int g = blockIdx.x * 256 + threadIdx.x;
    if (g < N_NODES) row_ptr[g] = partial[g] + boff[blockIdx.x];
    if (g == 0) row_ptr[N_NODES] = boff[NB_SCAN];
}

__global__ void k_tails(const int* __restrict__ row_ptr, int* __restrict__ gtail) {
    int t = threadIdx.x;
    if (t < NB) gtail[t] = row_ptr[dstart(t)];
}

// pass B: LDS-staged partition of (src,dst) into 128 dst-buckets, 256B flushes
__global__ void k_partB(const int* __restrict__ src, const int* __restrict__ dst,
                        int* __restrict__ gtail, uint2* __restrict__ staged) {
    __shared__ uint2 sbuf[NB][BDEPTH];
    __shared__ int scnt[NB];
    __shared__ int fn[NB];
    __shared__ int fbase[NB];
    int tid = threadIdx.x;   // 256
    for (int i = tid; i < NB; i += 256) scnt[i] = 0;
    __syncthreads();

    int e0 = blockIdx.x * EPB;
    int eend = e0 + EPB;
    if (eend > N_EDGES) eend = N_EDGES;

    for (int r = e0; r < eend; r += 256) {
        int e = r + tid;
        if (e < eend) {
            int d = dst[e], s = src[e];
            int b = bucket_of(d);
            int p = atomicAdd(&scnt[b], 1);
            if (p < BDEPTH) {
                sbuf[b][p] = make_uint2((unsigned)s, (unsigned)d);
            } else {
                atomicSub(&scnt[b], 1);
                int g = atomicAdd(&gtail[b], 1);
                staged[g] = make_uint2((unsigned)s, (unsigned)d);
            }
        }
        __syncthreads();
        if (tid < NB) {
            int c = scnt[tid];
            int f = (c / FLUSH) * FLUSH;
            fn[tid] = f;
            fbase[tid] = f ? atomicAdd(&gtail[tid], f) : 0;
        }
        __syncthreads();
        {
            int b2 = tid >> 1;
            int f = fn[b2];
            int gb = fbase[b2];
            for (int i = (tid & 1); i < f; i += 2) staged[gb + i] = sbuf[b2][i];
        }
        __syncthreads();
        if (tid < NB) {
            int f = fn[tid], c = scnt[tid];
            for (int i = f; i < c; ++i) sbuf[tid][i - f] = sbuf[tid][i];
            scnt[tid] = c - f;
        }
        __syncthreads();
    }
    // final flush of residuals
    if (tid < NB) {
        int c = scnt[tid];
        fn[tid] = c;
        fbase[tid] = c ? atomicAdd(&gtail[tid], c) : 0;
    }
    __syncthreads();
    {
        int b2 = tid >> 1;
        int f = fn[b2];
        int gb = fbase[b2];
        for (int i = (tid & 1); i < f; i += 2) staged[gb + i] = sbuf[b2][i];
    }
}

// pass C: per-bucket exact grouping into CSR col_src (writes confined to bucket window)
__global__ void k_partC(const uint2* __restrict__ staged, const int* __restrict__ row_ptr,
                        int* __restrict__ col_src) {
    __shared__ int fill[512];
    int b = blockIdx.x, tid = threadIdx.x;
    int d0 = dstart(b), d1 = dstart(b + 1);
    for (int i = tid; i < d1 - d0; i += 256) fill[i] = 0;
    __syncthreads();
    int e0 = row_ptr[d0], e1 = row_ptr[d1];
    for (int e = e0 + tid; e < e1; e += 256) {
        uint2 sd = staged[e];
        int d = (int)sd.y;
        int p = row_ptr[d] + atomicAdd(&fill[d - d0], 1);
        col_src[p] = (int)sd.x;
    }
}

// ---------------- GEMM: H = relu_bn(Z) @ W, fused BN+ReLU on load (mu==null -> raw)
__global__ void k_gemm(const float* __restrict__ Z, const float* __restrict__ W,
                       float* __restrict__ H, unsigned short* __restrict__ Hb,
                       const float* __restrict__ mu, const float* __restrict__ rs) {
    __shared__ float zT[128][36];
    __shared__ float Ws[64][128];
    int tid = threadIdx.x;
    int row0 = blockIdx.x * 32;

    for (int i = tid; i < 32 * 128; i += 256) {
        int r = i >> 7;
        int k = i & 127;
        int gr = row0 + r;
        float v = (gr < N_NODES) ? Z[(size_t)gr * 128 + k] : 0.f;
        if (mu) v = fmaxf((v - mu[k]) * rs[k], 0.f);
        zT[k][r] = v;
    }

    float acc[4][4];
#pragma unroll
    for (int a = 0; a < 4; a++)
#pragma unroll
        for (int b = 0; b < 4; b++) acc[a][b] = 0.f;

    int cg = tid & 31;
    int rg = tid >> 5;

    for (int kc = 0; kc < 2; ++kc) {
        __syncthreads();
        for (int i = tid; i < 64 * 128 / 4; i += 256) {
            int k = i >> 5;
            int c4 = i & 31;
            *(float4*)&Ws[k][c4 * 4] = *(const float4*)&W[(kc * 64 + k) * 128 + c4 * 4];
        }
        __syncthreads();
#pragma unroll 8
        for (int kk = 0; kk < 64; ++kk) {
            int k = kc * 64 + kk;
            float4 wv = *(float4*)&Ws[kk][cg * 4];
            float4 zv = *(float4*)&zT[k][rg * 4];
            acc[0][0] += zv.x * wv.x; acc[0][1] += zv.x * wv.y; acc[0][2] += zv.x * wv.z; acc[0][3] += zv.x * wv.w;
            acc[1][0] += zv.y * wv.x; acc[1][1] += zv.y * wv.y; acc[1][2] += zv.y * wv.z; acc[1][3] += zv.y * wv.w;
            acc[2][0] += zv.z * wv.x; acc[2][1] += zv.z * wv.y; acc[2][2] += zv.z * wv.z; acc[2][3] += zv.z * wv.w;
            acc[3][0] += zv.w * wv.x; acc[3][1] += zv.w * wv.y; acc[3][2] += zv.w * wv.z; acc[3][3] += zv.w * wv.w;
        }
    }

#pragma unroll
    for (int a = 0; a < 4; a++) {
        int gr = row0 + rg * 4 + a;
        if (gr < N_NODES) {
            *(float4*)&H[(size_t)gr * 128 + cg * 4] =
                make_float4(acc[a][0], acc[a][1], acc[a][2], acc[a][3]);
            ushort4 hb;
            hb.x = f2bf(acc[a][0]); hb.y = f2bf(acc[a][1]);
            hb.z = f2bf(acc[a][2]); hb.w = f2bf(acc[a][3]);
            *(ushort4*)&Hb[(size_t)gr * 128 + cg * 4] = hb;
        }
    }
}

// ---------------- per-node attention coefficients
__global__ void k_alpha(const float* __restrict__ H, const float* __restrict__ a_src,
                        const float* __restrict__ a_dst, float* __restrict__ as_,
                        float* __restrict__ ad_) {
    int node = blockIdx.x * 4 + (threadIdx.x >> 6);
    int lane = threadIdx.x & 63;
    if (node >= N_NODES) return;
    float2 h = *(const float2*)&H[(size_t)node * 128 + lane * 2];
    float2 s = *(const float2*)&a_src[lane * 2];
    float2 d = *(const float2*)&a_dst[lane * 2];
    float ps = h.x * s.x + h.y * s.y;
    float pd = h.x * d.x + h.y * d.y;
#pragma unroll
    for (int off = 32; off; off >>= 1) {
        ps += __shfl_xor(ps, off);
        pd += __shfl_xor(pd, off);
    }
    if (lane == 0) { as_[node] = ps; ad_[node] = pd; }
}

// ---------------- segment softmax + weighted aggregation (one wave per dst node)
__global__ void k_aggregate(const int* __restrict__ row_ptr, const int* __restrict__ col_src,
                            const unsigned short* __restrict__ Hb,
                            const float* __restrict__ as_, const float* __restrict__ ad_,
                            const float* __restrict__ bias, float* __restrict__ Zout,
                            float* __restrict__ ebuf) {
    int node = blockIdx.x * 4 + (threadIdx.x >> 6);
    int lane = threadIdx.x & 63;
    if (node >= N_NODES) return;

    int start = row_ptr[node], end = row_ptr[node + 1];
    int deg = end - start;
    float ad_i = ad_[node];
    float eself = lrelu(as_[node] + ad_i);
    float m = eself;
    float2 acc;
    float2 hi = ldh2(&Hb[(size_t)node * 128 + lane * 2]);

    if (deg <= 128) {
        int s0 = 0, s1 = 0;
        float e0 = -INFINITY, e1 = -INFINITY;
        if (start + lane < end) {
            s0 = col_src[start + lane];
            e0 = lrelu(as_[s0] + ad_i);
            m = fmaxf(m, e0);
        }
        if (start + 64 + lane < end) {
            s1 = col_src[start + 64 + lane];
            e1 = lrelu(as_[s1] + ad_i);
            m = fmaxf(m, e1);
        }
#pragma unroll
        for (int off = 32; off; off >>= 1) m = fmaxf(m, __shfl_xor(m, off));
        float w0 = __expf(e0 - m);
        float w1 = __expf(e1 - m);
        float p = w0 + w1;
#pragma unroll
        for (int off = 32; off; off >>= 1) p += __shfl_xor(p, off);
        float pself = __expf(eself - m);
        float inv_s = 1.f / (p + pself);
        w0 *= inv_s;
        w1 *= inv_s;
        float wself = pself * inv_s;
        acc.x = wself * hi.x;
        acc.y = wself * hi.y;

        int jmax = deg < 64 ? deg : 64;
        int j = 0;
        for (; j + 8 <= jmax; j += 8) {
            float w[8]; int sv[8];
#pragma unroll
            for (int q = 0; q < 8; ++q) {
                w[q] = __shfl(w0, j + q);
                sv[q] = __shfl(s0, j + q);
            }
            float2 h[8];
#pragma unroll
            for (int q = 0; q < 8; ++q) h[q] = ldh2(&Hb[(size_t)sv[q] * 128 + lane * 2]);
#pragma unroll
            for (int q = 0; q < 8; ++q) {
                acc.x += w[q] * h[q].x;
                acc.y += w[q] * h[q].y;
            }
        }
        for (; j < jmax; ++j) {
            float w = __shfl(w0, j);
            int sv = __shfl(s0, j);
            float2 hs = ldh2(&Hb[(size_t)sv * 128 + lane * 2]);
            acc.x += w * hs.x;
            acc.y += w * hs.y;
        }
        for (j = 64; j < deg; ++j) {
            float w = __shfl(w1, j - 64);
            int sv = __shfl(s1, j - 64);
            float2 hs = ldh2(&Hb[(size_t)sv * 128 + lane * 2]);
            acc.x += w * hs.x;
            acc.y += w * hs.y;
        }
    } else {
        for (int j = start + lane; j < end; j += 64) {
            int sj = col_src[j];
            float e = lrelu(as_[sj] + ad_i);
            ebuf[j] = e;
            m = fmaxf(m, e);
        }
#pragma unroll
        for (int off = 32; off; off >>= 1) m = fmaxf(m, __shfl_xor(m, off));
        float p = 0.f;
        for (int j = start + lane; j < end; j += 64) p += __expf(ebuf[j] - m);
#pragma unroll
        for (int off = 32; off; off >>= 1) p += __shfl_xor(p, off);
        float pself = __expf(eself - m);
        float inv_s = 1.f / (p + pself);
        float wself = pself * inv_s;
        acc.x = wself * hi.x;
        acc.y = wself * hi.y;
        for (int j = start; j < end; ++j) {
            int sv = col_src[j];
            float w = __expf(ebuf[j] - m) * inv_s;
            float2 hs = ldh2(&Hb[(size_t)sv * 128 + lane * 2]);
            acc.x += w * hs.x;
            acc.y += w * hs.y;
        }
    }

    float2 bv = *(const float2*)&bias[lane * 2];
    float2 o;
    o.x = acc.x + bv.x;
    o.y = acc.y + bv.y;
    *(float2*)&Zout[(size_t)node * 128 + lane * 2] = o;
}

// ---------------- BatchNorm stats (training, biased var)
__global__ void k_bnstats(const float* __restrict__ Z, float* __restrict__ part) {
    int c = threadIdx.x;
    float s = 0.f, sq = 0.f;
    for (int i = blockIdx.x; i < N_NODES; i += gridDim.x) {
        float v = Z[(size_t)i * 128 + c];
        s += v;
        sq += v * v;
    }
    part[blockIdx.x * 256 + c] = s;
    part[blockIdx.x * 256 + 128 + c] = sq;
}

__global__ void k_bnfinal(const float* __restrict__ part, float* __restrict__ mu,
                          float* __restrict__ rs) {
    int c = threadIdx.x;
    float s = 0.f, sq = 0.f;
    for (int b = 0; b < 512; ++b) {
        s += part[b * 256 + c];
        sq += part[b * 256 + 128 + c];
    }
    float m = s / (float)N_NODES;
    float var = sq / (float)N_NODES - m * m;
    mu[c] = m;
    rs[c] = rsqrtf(var + EPS);
}

__global__ void k_bnapply(const float* __restrict__ Zin, const float* __restrict__ mu,
                          const float* __restrict__ rs, float* __restrict__ Zout) {
    int idx = blockIdx.x * blockDim.x + threadIdx.x;
    if (idx >= N_NODES * 32) return;
    int c4 = idx & 31;
    float4 v = ((const float4*)Zin)[idx];
    float4 m4 = ((const float4*)mu)[c4];
    float4 r4 = ((const float4*)rs)[c4];
    v.x = fmaxf((v.x - m4.x) * r4.x, 0.f);
    v.y = fmaxf((v.y - m4.y) * r4.y, 0.f);
    v.z = fmaxf((v.z - m4.z) * r4.z, 0.f);
    v.w = fmaxf((v.w - m4.w) * r4.w, 0.f);
    ((float4*)Zout)[idx] = v;
}

extern "C" void kernel_launch(void* const* d_in, const int* in_sizes, int n_in,
                              void* d_out, int out_size, void* d_ws, size_t ws_size,
                              hipStream_t stream) {
    const float* x = (const float*)d_in[0];
    const int* ei = (const int*)d_in[1];
    const int* srcp = ei;
    const int* dstp = ei + N_EDGES;
    const float* W = (const float*)d_in[2];
    const float* a_src = (const float*)d_in[3];
    const float* a_dst = (const float*)d_in[4];
    const float* bias = (const float*)d_in[5];
    float* out = (float*)d_out;

    char* ws = (char*)d_ws;
    size_t off = 0;
    auto alloc = [&](size_t bytes) -> void* {
        void* p = ws + off;
        off = (off + bytes + 255) & ~(size_t)255;
        return p;
    };
    int* deg      = (int*)alloc(N_NODES * 4);
    int* row_ptr  = (int*)alloc((N_NODES + 1) * 4);
    int* col_src  = (int*)alloc(N_EDGES * 4);
    uint2* staged = (uint2*)alloc((size_t)N_EDGES * 8);   // also aliases ebuf + scan temps
    float* hbuf   = (float*)alloc((size_t)N_NODES * DIM * 4);
    unsigned short* hbf = (unsigned short*)alloc((size_t)N_NODES * DIM * 2);
    float* zbuf   = (float*)alloc((size_t)N_NODES * DIM * 4);
    float* asb    = (float*)alloc(N_NODES * 4);
    float* adb    = (float*)alloc(N_NODES * 4);
    float* part   = (float*)alloc(512 * 256 * 4);
    float* mu     = (float*)alloc(128 * 4);
    float* rsg    = (float*)alloc(128 * 4);
    int* gtail    = (int*)alloc(NB * 4);
    if (off > ws_size) return;

    // aliases into `staged` (temporally disjoint uses)
    float* ebuf  = (float*)staged;          // used only inside k_aggregate (after partC)
    int* partial = (int*)staged;            // scan temps (before partB writes staged)
    int* bsum    = partial + N_NODES;
    int* boff    = bsum + 256;

    hipMemsetAsync(deg, 0, N_NODES * 4, stream);
    k_degree<<<(N_EDGES / 4 + 255) / 256, 256, 0, stream>>>(dstp, deg);
    k_scan1<<<NB_SCAN, 256, 0, stream>>>(deg, partial, bsum);
    k_scan2<<<1, 256, 0, stream>>>(bsum, boff);
    k_scan3<<<NB_SCAN, 256, 0, stream>>>(partial, boff, row_ptr);
    k_tails<<<1, NB, 0, stream>>>(row_ptr, gtail);
    k_partB<<<NBLK_B, 256, 0, stream>>>(srcp, dstp, gtail, staged);
    k_partC<<<NB, 256, 0, stream>>>(staged, row_ptr, col_src);

    const float* zin = x;
    for (int l = 0; l < 3; ++l) {
        k_gemm<<<(N_NODES + 31) / 32, 256, 0, stream>>>(
            zin, W + l * DIM * DIM, hbuf, hbf, (l == 0) ? nullptr : mu, rsg);
        k_alpha<<<(N_NODES + 3) / 4, 256, 0, stream>>>(hbuf, a_src + l * DIM, a_dst + l * DIM,
                                                       asb, adb);
        k_aggregate<<<(N_NODES + 3) / 4, 256, 0, stream>>>(row_ptr, col_src, hbf, asb, adb,
                                                           bias + l * DIM, zbuf, ebuf);
        k_bnstats<<<512, 128, 0, stream>>>(zbuf, part);
        k_bnfinal<<<1, 128, 0, stream>>>(part, mu, rsg);
        if (l == 2)
            k_bnapply<<<(N_NODES * 32 + 255) / 256, 256, 0, stream>>>(zbuf, mu, rsg, out);
        zin = zbuf;
    }
}

// Round 4
// 638.410 us; speedup vs baseline: 1.1709x; 1.1709x over previous
//
#include <hip/hip_runtime.h>
#include <hip/hip_bf16.h>
#include <math.h>

#define N_NODES 50000
#define N_EDGES 1600000
#define DIM 128
#define EPS 1e-5f
#define SLOPE 0.2f
#define NB_SCAN 196   // ceil(50000/256)
#define NRANGE 8      // dst ranges for scatter (XCD-aligned via blockIdx&7)

typedef __attribute__((ext_vector_type(8))) short bf16x8;
typedef __attribute__((ext_vector_type(4))) float f32x4;

__device__ __forceinline__ float lrelu(float x) { return x > 0.f ? x : SLOPE * x; }

__device__ __forceinline__ unsigned short f2bf(float f) {
    unsigned u = __float_as_uint(f);
    unsigned r = (u + 0x7fffu + ((u >> 16) & 1u)) >> 16;
    return (unsigned short)r;
}

__device__ __forceinline__ float2 ldh2(const unsigned short* p) {
    unsigned u = *(const unsigned*)p;
    float2 r;
    r.x = __uint_as_float(u << 16);
    r.y = __uint_as_float(u & 0xffff0000u);
    return r;
}

// ---------------- CSR build ----------------
__global__ void k_degree(const int* __restrict__ dst, int* __restrict__ deg) {
    int i = blockIdx.x * blockDim.x + threadIdx.x;
    if (i < N_EDGES / 4) {
        int4 d = ((const int4*)dst)[i];
        atomicAdd(&deg[d.x], 1);
        atomicAdd(&deg[d.y], 1);
        atomicAdd(&deg[d.z], 1);
        atomicAdd(&deg[d.w], 1);
    }
}

__global__ void k_scan1(const int* __restrict__ deg, int* __restrict__ partial,
                        int* __restrict__ bsum) {
    __shared__ int s[256];
    int t = threadIdx.x, g = blockIdx.x * 256 + t;
    int v = (g < N_NODES) ? deg[g] : 0;
    s[t] = v;
    __syncthreads();
    for (int off = 1; off < 256; off <<= 1) {
        int x = s[t];
        int y = (t >= off) ? s[t - off] : 0;
        __syncthreads();
        s[t] = x + y;
        __syncthreads();
    }
    if (g < N_NODES) partial[g] = s[t] - v;
    if (t == 255) bsum[blockIdx.x] = s[255];
}

__global__ void k_scan2(const int* __restrict__ bsum, int* __restrict__ boff) {
    __shared__ int s[256];
    int t = threadIdx.x;
    int v = (t < NB_SCAN) ? bsum[t] : 0;
    s[t] = v;
    __syncthreads();
    for (int off = 1; off < 256; off <<= 1) {
        int x = s[t];
        int y = (t >= off) ? s[t - off] : 0;
        __syncthreads();
        s[t] = x + y;
        __syncthreads();
    }
    if (t < NB_SCAN) boff[t] = s[t] - v;
    if (t == 255) boff[NB_SCAN] = s[255];
}

__global__ void k_scan3(const int* __restrict__ partial, const int* __restrict__ boff,
                        int* __restrict__ row_ptr) {
    int g = blockIdx.x * 256 + threadIdx.x;
    if (g < N_NODES) row_ptr[g] = partial[g] + boff[blockIdx.x];
    if (g == 0) row_ptr[N_NODES] = boff[NB_SCAN];
}

// range-filtered scatter: blocks of range r only place edges with dst in range r.
// Keeps fill[] atomics + col_src[] writes in a ~25KB/800KB window (L2-resident).
__global__ void k_scatter_r(const int* __restrict__ src, const int* __restrict__ dst,
                            const int* __restrict__ row_ptr, int* __restrict__ fill,
                            int* __restrict__ col_src) {
    int range = blockIdx.x & (NRANGE - 1);
    int blk = blockIdx.x >> 3;
    int nblk = gridDim.x >> 3;
    int lo = range * (N_NODES / NRANGE);
    int hi = (range == NRANGE - 1) ? N_NODES : lo + (N_NODES / NRANGE);
    int nq = N_EDGES / 4;
    for (int q = blk * blockDim.x + threadIdx.x; q < nq; q += nblk * blockDim.x) {
        int4 d4 = ((const int4*)dst)[q];
        if (d4.x >= lo && d4.x < hi) {
            int pos = row_ptr[d4.x] + atomicAdd(&fill[d4.x], 1);
            col_src[pos] = src[q * 4 + 0];
        }
        if (d4.y >= lo && d4.y < hi) {
            int pos = row_ptr[d4.y] + atomicAdd(&fill[d4.y], 1);
            col_src[pos] = src[q * 4 + 1];
        }
        if (d4.z >= lo && d4.z < hi) {
            int pos = row_ptr[d4.z] + atomicAdd(&fill[d4.z], 1);
            col_src[pos] = src[q * 4 + 2];
        }
        if (d4.w >= lo && d4.w < hi) {
            int pos = row_ptr[d4.w] + atomicAdd(&fill[d4.w], 1);
            col_src[pos] = src[q * 4 + 3];
        }
    }
}

// ---------------- prep: W[l] (fp32 [k][c]) -> Wt (bf16 [c][k]), all 3 layers
__global__ void k_prepW(const float* __restrict__ W, unsigned short* __restrict__ Wt) {
    int idx = blockIdx.x * 256 + threadIdx.x;   // 3*128*128
    int l = idx >> 14;
    int k = (idx >> 7) & 127;
    int c = idx & 127;
    Wt[l * 16384 + c * 128 + k] = f2bf(W[l * 16384 + k * 128 + c]);
}

// ---------------- cast x -> bf16
__global__ void k_castx(const float* __restrict__ X, unsigned short* __restrict__ Zb) {
    int idx = blockIdx.x * blockDim.x + threadIdx.x;   // N*16 groups of 8
    if (idx >= N_NODES * 16) return;
    size_t base = (size_t)idx * 8;
    float4 a = *(const float4*)&X[base];
    float4 b = *(const float4*)&X[base + 4];
    uint4 o;
    o.x = (unsigned)f2bf(a.x) | ((unsigned)f2bf(a.y) << 16);
    o.y = (unsigned)f2bf(a.z) | ((unsigned)f2bf(a.w) << 16);
    o.z = (unsigned)f2bf(b.x) | ((unsigned)f2bf(b.y) << 16);
    o.w = (unsigned)f2bf(b.z) | ((unsigned)f2bf(b.w) << 16);
    *(uint4*)&Zb[base] = o;
}

// ---------------- MFMA GEMM: H = Zb @ W  (bf16 in, fp32 out + bf16 copy)
// block: 256 thr = 4 waves; 128 rows/block; W tile staged bf16 in LDS, XOR-swizzled.
__global__ __launch_bounds__(256) void k_gemm_mfma(const unsigned short* __restrict__ Zb,
                                                   const unsigned short* __restrict__ Wt,
                                                   float* __restrict__ H,
                                                   unsigned short* __restrict__ Hb) {
    __shared__ unsigned short Bs[128 * 128];
    int tid = threadIdx.x;
    int lane = tid & 63, wave = tid >> 6;

    {   // stage Wt[c][k] -> Bs swizzled: byte = (c*256 + k*2) ^ ((c&7)<<4)
        int c = tid >> 1, kh = tid & 1;
        const unsigned short* gsrc = &Wt[c * 128 + kh * 64];
#pragma unroll
        for (int ch = 0; ch < 8; ++ch) {
            int byte_off = (c * 256 + kh * 128 + ch * 16) ^ ((c & 7) << 4);
            *(int4*)((char*)Bs + byte_off) = *(const int4*)(gsrc + ch * 8);
        }
    }

    int r0 = blockIdx.x * 128 + wave * 32;
    bf16x8 afr[2][4];
#pragma unroll
    for (int rt = 0; rt < 2; ++rt) {
        int row = r0 + rt * 16 + (lane & 15);
#pragma unroll
        for (int ks = 0; ks < 4; ++ks) {
            int k = ks * 32 + (lane >> 4) * 8;
            if (row < N_NODES)
                afr[rt][ks] = *(const bf16x8*)&Zb[(size_t)row * 128 + k];
            else
                afr[rt][ks] = (bf16x8){0, 0, 0, 0, 0, 0, 0, 0};
        }
    }
    __syncthreads();

    f32x4 acc[2][8];
#pragma unroll
    for (int rt = 0; rt < 2; ++rt)
#pragma unroll
        for (int ct = 0; ct < 8; ++ct) acc[rt][ct] = (f32x4){0.f, 0.f, 0.f, 0.f};

#pragma unroll
    for (int ct = 0; ct < 8; ++ct) {
        int c = ct * 16 + (lane & 15);
#pragma unroll
        for (int ks = 0; ks < 4; ++ks) {
            int k = ks * 32 + (lane >> 4) * 8;
            int byte_off = (c * 256 + k * 2) ^ ((c & 7) << 4);
            bf16x8 bfr = *(const bf16x8*)((char*)Bs + byte_off);
            acc[0][ct] = __builtin_amdgcn_mfma_f32_16x16x32_bf16(afr[0][ks], bfr, acc[0][ct], 0, 0, 0);
            acc[1][ct] = __builtin_amdgcn_mfma_f32_16x16x32_bf16(afr[1][ks], bfr, acc[1][ct], 0, 0, 0);
        }
    }

#pragma unroll
    for (int rt = 0; rt < 2; ++rt)
#pragma unroll
        for (int ct = 0; ct < 8; ++ct) {
            int c = ct * 16 + (lane & 15);
#pragma unroll
            for (int j = 0; j < 4; ++j) {
                int row = r0 + rt * 16 + (lane >> 4) * 4 + j;
                if (row < N_NODES) {
                    float v = acc[rt][ct][j];
                    H[(size_t)row * 128 + c] = v;
                    Hb[(size_t)row * 128 + c] = f2bf(v);
                }
            }
        }
}

// ---------------- per-node attention coefficients
__global__ void k_alpha(const float* __restrict__ H, const float* __restrict__ a_src,
                        const float* __restrict__ a_dst, float* __restrict__ as_,
                        float* __restrict__ ad_) {
    int node = blockIdx.x * 4 + (threadIdx.x >> 6);
    int lane = threadIdx.x & 63;
    if (node >= N_NODES) return;
    float2 h = *(const float2*)&H[(size_t)node * 128 + lane * 2];
    float2 s = *(const float2*)&a_src[lane * 2];
    float2 d = *(const float2*)&a_dst[lane * 2];
    float ps = h.x * s.x + h.y * s.y;
    float pd = h.x * d.x + h.y * d.y;
#pragma unroll
    for (int off = 32; off; off >>= 1) {
        ps += __shfl_xor(ps, off);
        pd += __shfl_xor(pd, off);
    }
    if (lane == 0) { as_[node] = ps; ad_[node] = pd; }
}

// ---------------- segment softmax + weighted aggregation (one wave per dst node)
__global__ void k_aggregate(const int* __restrict__ row_ptr, const int* __restrict__ col_src,
                            const unsigned short* __restrict__ Hb,
                            const float* __restrict__ as_, const float* __restrict__ ad_,
                            const float* __restrict__ bias, float* __restrict__ Zout,
                            float* __restrict__ ebuf) {
    int node = blockIdx.x * 4 + (threadIdx.x >> 6);
    int lane = threadIdx.x & 63;
    if (node >= N_NODES) return;

    int start = row_ptr[node], end = row_ptr[node + 1];
    int deg = end - start;
    float ad_i = ad_[node];
    float eself = lrelu(as_[node] + ad_i);
    float m = eself;
    float2 acc;
    float2 hi = ldh2(&Hb[(size_t)node * 128 + lane * 2]);

    if (deg <= 128) {
        int s0 = 0, s1 = 0;
        float e0 = -INFINITY, e1 = -INFINITY;
        if (start + lane < end) {
            s0 = col_src[start + lane];
            e0 = lrelu(as_[s0] + ad_i);
            m = fmaxf(m, e0);
        }
        if (start + 64 + lane < end) {
            s1 = col_src[start + 64 + lane];
            e1 = lrelu(as_[s1] + ad_i);
            m = fmaxf(m, e1);
        }
#pragma unroll
        for (int off = 32; off; off >>= 1) m = fmaxf(m, __shfl_xor(m, off));
        float w0 = __expf(e0 - m);
        float w1 = __expf(e1 - m);
        float p = w0 + w1;
#pragma unroll
        for (int off = 32; off; off >>= 1) p += __shfl_xor(p, off);
        float pself = __expf(eself - m);
        float inv_s = 1.f / (p + pself);
        w0 *= inv_s;
        w1 *= inv_s;
        float wself = pself * inv_s;
        acc.x = wself * hi.x;
        acc.y = wself * hi.y;

        int jmax = deg < 64 ? deg : 64;
        int j = 0;
        for (; j + 8 <= jmax; j += 8) {
            float w[8]; int sv[8];
#pragma unroll
            for (int q = 0; q < 8; ++q) {
                w[q] = __shfl(w0, j + q);
                sv[q] = __shfl(s0, j + q);
            }
            float2 h[8];
#pragma unroll
            for (int q = 0; q < 8; ++q) h[q] = ldh2(&Hb[(size_t)sv[q] * 128 + lane * 2]);
#pragma unroll
            for (int q = 0; q < 8; ++q) {
                acc.x += w[q] * h[q].x;
                acc.y += w[q] * h[q].y;
            }
        }
        for (; j < jmax; ++j) {
            float w = __shfl(w0, j);
            int sv = __shfl(s0, j);
            float2 hs = ldh2(&Hb[(size_t)sv * 128 + lane * 2]);
            acc.x += w * hs.x;
            acc.y += w * hs.y;
        }
        for (j = 64; j < deg; ++j) {
            float w = __shfl(w1, j - 64);
            int sv = __shfl(s1, j - 64);
            float2 hs = ldh2(&Hb[(size_t)sv * 128 + lane * 2]);
            acc.x += w * hs.x;
            acc.y += w * hs.y;
        }
    } else {
        for (int j = start + lane; j < end; j += 64) {
            int sj = col_src[j];
            float e = lrelu(as_[sj] + ad_i);
            ebuf[j] = e;
            m = fmaxf(m, e);
        }
#pragma unroll
        for (int off = 32; off; off >>= 1) m = fmaxf(m, __shfl_xor(m, off));
        float p = 0.f;
        for (int j = start + lane; j < end; j += 64) p += __expf(ebuf[j] - m);
#pragma unroll
        for (int off = 32; off; off >>= 1) p += __shfl_xor(p, off);
        float pself = __expf(eself - m);
        float inv_s = 1.f / (p + pself);
        float wself = pself * inv_s;
        acc.x = wself * hi.x;
        acc.y = wself * hi.y;
        for (int j = start; j < end; ++j) {
            int sv = col_src[j];
            float w = __expf(ebuf[j] - m) * inv_s;
            float2 hs = ldh2(&Hb[(size_t)sv * 128 + lane * 2]);
            acc.x += w * hs.x;
            acc.y += w * hs.y;
        }
    }

    float2 bv = *(const float2*)&bias[lane * 2];
    float2 o;
    o.x = acc.x + bv.x;
    o.y = acc.y + bv.y;
    *(float2*)&Zout[(size_t)node * 128 + lane * 2] = o;
}

// ---------------- BatchNorm stats (training, biased var)
__global__ void k_bnstats(const float* __restrict__ Z, float* __restrict__ part) {
    int c = threadIdx.x;
    float s = 0.f, sq = 0.f;
    for (int i = blockIdx.x; i < N_NODES; i += gridDim.x) {
        float v = Z[(size_t)i * 128 + c];
        s += v;
        sq += v * v;
    }
    part[blockIdx.x * 256 + c] = s;
    part[blockIdx.x * 256 + 128 + c] = sq;
}

__global__ void k_bnfinal(const float* __restrict__ part, float* __restrict__ mu,
                          float* __restrict__ rs) {
    int c = threadIdx.x;
    float s = 0.f, sq = 0.f;
    for (int b = 0; b < 512; ++b) {
        s += part[b * 256 + c];
        sq += part[b * 256 + 128 + c];
    }
    float m = s / (float)N_NODES;
    float var = sq / (float)N_NODES - m * m;
    mu[c] = m;
    rs[c] = rsqrtf(var + EPS);
}

// BN+ReLU apply; writes bf16 zb (next GEMM input) and/or fp32 out (final layer)
__global__ void k_bnapply2(const float* __restrict__ Zin, const float* __restrict__ mu,
                           const float* __restrict__ rs, float* __restrict__ outf,
                           unsigned short* __restrict__ outb) {
    int idx = blockIdx.x * blockDim.x + threadIdx.x;   // N*16 groups of 8
    if (idx >= N_NODES * 16) return;
    size_t base = (size_t)idx * 8;
    int c = (int)(base & 127);
    float4 a = *(const float4*)&Zin[base];
    float4 b = *(const float4*)&Zin[base + 4];
    float4 m0 = *(const float4*)&mu[c];
    float4 m1 = *(const float4*)&mu[c + 4];
    float4 r0 = *(const float4*)&rs[c];
    float4 r1 = *(const float4*)&rs[c + 4];
    a.x = fmaxf((a.x - m0.x) * r0.x, 0.f);
    a.y = fmaxf((a.y - m0.y) * r0.y, 0.f);
    a.z = fmaxf((a.z - m0.z) * r0.z, 0.f);
    a.w = fmaxf((a.w - m0.w) * r0.w, 0.f);
    b.x = fmaxf((b.x - m1.x) * r1.x, 0.f);
    b.y = fmaxf((b.y - m1.y) * r1.y, 0.f);
    b.z = fmaxf((b.z - m1.z) * r1.z, 0.f);
    b.w = fmaxf((b.w - m1.w) * r1.w, 0.f);
    if (outf) {
        *(float4*)&outf[base] = a;
        *(float4*)&outf[base + 4] = b;
    }
    if (outb) {
        uint4 o;
        o.x = (unsigned)f2bf(a.x) | ((unsigned)f2bf(a.y) << 16);
        o.y = (unsigned)f2bf(a.z) | ((unsigned)f2bf(a.w) << 16);
        o.z = (unsigned)f2bf(b.x) | ((unsigned)f2bf(b.y) << 16);
        o.w = (unsigned)f2bf(b.z) | ((unsigned)f2bf(b.w) << 16);
        *(uint4*)&outb[base] = o;
    }
}

extern "C" void kernel_launch(void* const* d_in, const int* in_sizes, int n_in,
                              void* d_out, int out_size, void* d_ws, size_t ws_size,
                              hipStream_t stream) {
    const float* x = (const float*)d_in[0];
    const int* ei = (const int*)d_in[1];
    const int* srcp = ei;
    const int* dstp = ei + N_EDGES;
    const float* W = (const float*)d_in[2];
    const float* a_src = (const float*)d_in[3];
    const float* a_dst = (const float*)d_in[4];
    const float* bias = (const float*)d_in[5];
    float* out = (float*)d_out;

    char* ws = (char*)d_ws;
    size_t off = 0;
    auto alloc = [&](size_t bytes) -> void* {
        void* p = ws + off;
        off = (off + bytes + 255) & ~(size_t)255;
        return p;
    };
    int* deg      = (int*)alloc(N_NODES * 4);
    int* fill     = (int*)alloc(N_NODES * 4);
    int* row_ptr  = (int*)alloc((N_NODES + 1) * 4);
    int* col_src  = (int*)alloc(N_EDGES * 4);
    float* ebuf   = (float*)alloc(N_EDGES * 4);            // aliases scan temps
    float* hbuf   = (float*)alloc((size_t)N_NODES * DIM * 4);
    unsigned short* hbf = (unsigned short*)alloc((size_t)N_NODES * DIM * 2);
    float* zbuf   = (float*)alloc((size_t)N_NODES * DIM * 4);
    unsigned short* zb = (unsigned short*)alloc((size_t)N_NODES * DIM * 2);
    unsigned short* wtb = (unsigned short*)alloc(3 * 16384 * 2);
    float* asb    = (float*)alloc(N_NODES * 4);
    float* adb    = (float*)alloc(N_NODES * 4);
    float* part   = (float*)alloc(512 * 256 * 4);
    float* mu     = (float*)alloc(128 * 4);
    float* rsg    = (float*)alloc(128 * 4);
    if (off > ws_size) return;

    // scan temporaries alias ebuf (scan finishes before any aggregate)
    int* partial = (int*)ebuf;
    int* bsum    = partial + N_NODES;
    int* boff    = bsum + 256;

    hipMemsetAsync(deg, 0, N_NODES * 4, stream);
    hipMemsetAsync(fill, 0, N_NODES * 4, stream);
    k_degree<<<(N_EDGES / 4 + 255) / 256, 256, 0, stream>>>(dstp, deg);
    k_scan1<<<NB_SCAN, 256, 0, stream>>>(deg, partial, bsum);
    k_scan2<<<1, 256, 0, stream>>>(bsum, boff);
    k_scan3<<<NB_SCAN, 256, 0, stream>>>(partial, boff, row_ptr);
    k_scatter_r<<<NRANGE * 128, 256, 0, stream>>>(srcp, dstp, row_ptr, fill, col_src);
    k_prepW<<<192, 256, 0, stream>>>(W, wtb);
    k_castx<<<(N_NODES * 16 + 255) / 256, 256, 0, stream>>>(x, zb);

    for (int l = 0; l < 3; ++l) {
        k_gemm_mfma<<<(N_NODES + 127) / 128, 256, 0, stream>>>(zb, wtb + l * 16384, hbuf, hbf);
        k_alpha<<<(N_NODES + 3) / 4, 256, 0, stream>>>(hbuf, a_src + l * DIM, a_dst + l * DIM,
                                                       asb, adb);
        k_aggregate<<<(N_NODES + 3) / 4, 256, 0, stream>>>(row_ptr, col_src, hbf, asb, adb,
                                                           bias + l * DIM, zbuf, ebuf);
        k_bnstats<<<512, 128, 0, stream>>>(zbuf, part);
        k_bnfinal<<<1, 128, 0, stream>>>(part, mu, rsg);
        k_bnapply2<<<(N_NODES * 16 + 255) / 256, 256, 0, stream>>>(
            zbuf, mu, rsg, (l == 2) ? out : nullptr, (l < 2) ? zb : nullptr);
    }
}

// Round 5
// 514.993 us; speedup vs baseline: 1.4515x; 1.2396x over previous
//
#include <hip/hip_runtime.h>
#include <hip/hip_bf16.h>
#include <math.h>

#define N_NODES 50000
#define N_EDGES 1600000
#define DIM 128
#define EPS 1e-5f
#define SLOPE 0.2f

#define NBUCK 256
#define NPB 196        // nodes per bucket (ceil 50000/256)
#define EPB 4096       // edges per partB block
#define NBLK_B ((N_EDGES + EPB - 1) / EPB)

typedef __attribute__((ext_vector_type(8))) short bf16x8;
typedef __attribute__((ext_vector_type(4))) float f32x4;

__device__ __forceinline__ float lrelu(float x) { return x > 0.f ? x : SLOPE * x; }

__device__ __forceinline__ unsigned short f2bf(float f) {
    unsigned u = __float_as_uint(f);
    unsigned r = (u + 0x7fffu + ((u >> 16) & 1u)) >> 16;
    return (unsigned short)r;
}

__device__ __forceinline__ float2 ldh2(const unsigned short* p) {
    unsigned u = *(const unsigned*)p;
    float2 r;
    r.x = __uint_as_float(u << 16);
    r.y = __uint_as_float(u & 0xffff0000u);
    return r;
}

// ---------------- build step 1: coarse bucket histogram (bucket = dst / 196)
__global__ void k_hist(const int* __restrict__ dst, int* __restrict__ bcnt) {
    __shared__ int h[NBUCK];
    int tid = threadIdx.x;
    h[tid] = 0;
    __syncthreads();
    int nq = N_EDGES / 4;
    for (int q = blockIdx.x * 256 + tid; q < nq; q += gridDim.x * 256) {
        int4 d = ((const int4*)dst)[q];
        atomicAdd(&h[d.x / NPB], 1);
        atomicAdd(&h[d.y / NPB], 1);
        atomicAdd(&h[d.z / NPB], 1);
        atomicAdd(&h[d.w / NPB], 1);
    }
    __syncthreads();
    if (h[tid]) atomicAdd(&bcnt[tid], h[tid]);
}

// ---------------- build step 2: scan bucket counts -> bases + gtail copy
__global__ void k_bscan(const int* __restrict__ bcnt, int* __restrict__ bbase,
                        int* __restrict__ gtail) {
    __shared__ int s[NBUCK];
    int t = threadIdx.x;
    int v = bcnt[t];
    s[t] = v;
    __syncthreads();
    for (int off = 1; off < NBUCK; off <<= 1) {
        int x = s[t];
        int y = (t >= off) ? s[t - off] : 0;
        __syncthreads();
        s[t] = x + y;
        __syncthreads();
    }
    bbase[t] = s[t] - v;
    gtail[t] = s[t] - v;
    if (t == NBUCK - 1) bbase[NBUCK] = s[NBUCK - 1];
}

// ---------------- build step 3: partition edges into bucket-segmented staged[]
__global__ __launch_bounds__(256) void k_partB(const int* __restrict__ src,
                                               const int* __restrict__ dst,
                                               int* __restrict__ gtail,
                                               uint2* __restrict__ staged) {
    __shared__ int cnt[NBUCK];
    __shared__ int bas[NBUCK];
    int tid = threadIdx.x;
    cnt[tid] = 0;
    __syncthreads();
    int e0 = blockIdx.x * EPB;
#pragma unroll 4
    for (int i = 0; i < EPB / 256; ++i) {
        int e = e0 + i * 256 + tid;
        if (e < N_EDGES) atomicAdd(&cnt[dst[e] / NPB], 1);
    }
    __syncthreads();
    {
        int c = cnt[tid];
        bas[tid] = c ? atomicAdd(&gtail[tid], c) : 0;
    }
    __syncthreads();
    cnt[tid] = 0;
    __syncthreads();
#pragma unroll 4
    for (int i = 0; i < EPB / 256; ++i) {
        int e = e0 + i * 256 + tid;
        if (e < N_EDGES) {
            int d = dst[e], s = src[e];
            int b = d / NPB;
            int off = atomicAdd(&cnt[b], 1);
            staged[bas[b] + off] = make_uint2((unsigned)s, (unsigned)d);
        }
    }
}

// ---------------- build step 4: per-bucket grouping; writes row_ptr AND col_src
__global__ __launch_bounds__(256) void k_partC(const uint2* __restrict__ staged,
                                               const int* __restrict__ bbase,
                                               int* __restrict__ row_ptr,
                                               int* __restrict__ col_src) {
    __shared__ int cnt[NBUCK];
    __shared__ int loc[NBUCK];
    __shared__ int s[NBUCK];
    int b = blockIdx.x, tid = threadIdx.x;
    int d0 = b * NPB;
    int d1 = d0 + NPB;
    if (d1 > N_NODES) d1 = N_NODES;
    int nn = d1 - d0;
    int s0 = bbase[b], s1 = bbase[b + 1];

    cnt[tid] = 0;
    __syncthreads();
    for (int e = s0 + tid; e < s1; e += 256) {
        int d = (int)staged[e].y;
        atomicAdd(&cnt[d - d0], 1);
    }
    __syncthreads();
    {   // exclusive scan of cnt -> loc
        int v = cnt[tid];
        s[tid] = v;
        __syncthreads();
        for (int off = 1; off < NBUCK; off <<= 1) {
            int x = s[tid];
            int y = (tid >= off) ? s[tid - off] : 0;
            __syncthreads();
            s[tid] = x + y;
            __syncthreads();
        }
        loc[tid] = s[tid] - v;
    }
    if (tid < nn) row_ptr[d0 + tid] = s0 + loc[tid];
    if (b == 0 && tid == 0) row_ptr[N_NODES] = N_EDGES;
    cnt[tid] = 0;
    __syncthreads();
    for (int e = s0 + tid; e < s1; e += 256) {
        uint2 sd = staged[e];
        int d = (int)sd.y;
        int pos = s0 + loc[d - d0] + atomicAdd(&cnt[d - d0], 1);
        col_src[pos] = (int)sd.x;
    }
}

// ---------------- prep: W[l] (fp32 [k][c]) -> Wt (bf16 [c][k]), all 3 layers
__global__ void k_prepW(const float* __restrict__ W, unsigned short* __restrict__ Wt) {
    int idx = blockIdx.x * 256 + threadIdx.x;
    int l = idx >> 14;
    int k = (idx >> 7) & 127;
    int c = idx & 127;
    Wt[l * 16384 + c * 128 + k] = f2bf(W[l * 16384 + k * 128 + c]);
}

// ---------------- MFMA GEMM with fused BN+ReLU input and fused alpha epilogue
// H_bf16 = bf16( bnrelu(Z) @ W );  as/ad = (Z@W) . a_src/a_dst  (fp32 acc)
__global__ __launch_bounds__(256) void k_gemm_mfma(const float* __restrict__ Z,
                                                   const unsigned short* __restrict__ Wt,
                                                   unsigned short* __restrict__ Hb,
                                                   const float* __restrict__ mu,
                                                   const float* __restrict__ rs,
                                                   const float* __restrict__ a_src,
                                                   const float* __restrict__ a_dst,
                                                   float* __restrict__ as_,
                                                   float* __restrict__ ad_) {
    __shared__ unsigned short Bs[128 * 128];
    int tid = threadIdx.x;
    int lane = tid & 63, wave = tid >> 6;

    {   // stage Wt[c][k] -> Bs swizzled: byte = (c*256 + k*2) ^ ((c&7)<<4)
        int c = tid >> 1, kh = tid & 1;
        const unsigned short* gsrc = &Wt[c * 128 + kh * 64];
#pragma unroll
        for (int ch = 0; ch < 8; ++ch) {
            int byte_off = (c * 256 + kh * 128 + ch * 16) ^ ((c & 7) << 4);
            *(int4*)((char*)Bs + byte_off) = *(const int4*)(gsrc + ch * 8);
        }
    }

    int r0 = blockIdx.x * 128 + wave * 32;
    bf16x8 afr[2][4];
#pragma unroll
    for (int rt = 0; rt < 2; ++rt) {
        int row = r0 + rt * 16 + (lane & 15);
        const float* zrow = &Z[(size_t)row * 128];
#pragma unroll
        for (int ks = 0; ks < 4; ++ks) {
            int k = ks * 32 + (lane >> 4) * 8;
            bf16x8 fr = (bf16x8){0, 0, 0, 0, 0, 0, 0, 0};
            if (row < N_NODES) {
                float4 a = *(const float4*)&zrow[k];
                float4 b = *(const float4*)&zrow[k + 4];
                if (mu) {
                    float4 m0 = *(const float4*)&mu[k];
                    float4 m1 = *(const float4*)&mu[k + 4];
                    float4 r0v = *(const float4*)&rs[k];
                    float4 r1v = *(const float4*)&rs[k + 4];
                    a.x = fmaxf((a.x - m0.x) * r0v.x, 0.f);
                    a.y = fmaxf((a.y - m0.y) * r0v.y, 0.f);
                    a.z = fmaxf((a.z - m0.z) * r0v.z, 0.f);
                    a.w = fmaxf((a.w - m0.w) * r0v.w, 0.f);
                    b.x = fmaxf((b.x - m1.x) * r1v.x, 0.f);
                    b.y = fmaxf((b.y - m1.y) * r1v.y, 0.f);
                    b.z = fmaxf((b.z - m1.z) * r1v.z, 0.f);
                    b.w = fmaxf((b.w - m1.w) * r1v.w, 0.f);
                }
                fr[0] = (short)f2bf(a.x); fr[1] = (short)f2bf(a.y);
                fr[2] = (short)f2bf(a.z); fr[3] = (short)f2bf(a.w);
                fr[4] = (short)f2bf(b.x); fr[5] = (short)f2bf(b.y);
                fr[6] = (short)f2bf(b.z); fr[7] = (short)f2bf(b.w);
            }
            afr[rt][ks] = fr;
        }
    }

    float asv[8], adv[8];
#pragma unroll
    for (int ct = 0; ct < 8; ++ct) {
        int c = ct * 16 + (lane & 15);
        asv[ct] = a_src[c];
        adv[ct] = a_dst[c];
    }
    __syncthreads();

    f32x4 acc[2][8];
#pragma unroll
    for (int rt = 0; rt < 2; ++rt)
#pragma unroll
        for (int ct = 0; ct < 8; ++ct) acc[rt][ct] = (f32x4){0.f, 0.f, 0.f, 0.f};

#pragma unroll
    for (int ct = 0; ct < 8; ++ct) {
        int c = ct * 16 + (lane & 15);
#pragma unroll
        for (int ks = 0; ks < 4; ++ks) {
            int k = ks * 32 + (lane >> 4) * 8;
            int byte_off = (c * 256 + k * 2) ^ ((c & 7) << 4);
            bf16x8 bfr = *(const bf16x8*)((char*)Bs + byte_off);
            acc[0][ct] = __builtin_amdgcn_mfma_f32_16x16x32_bf16(afr[0][ks], bfr, acc[0][ct], 0, 0, 0);
            acc[1][ct] = __builtin_amdgcn_mfma_f32_16x16x32_bf16(afr[1][ks], bfr, acc[1][ct], 0, 0, 0);
        }
    }

    // epilogue: bf16 H store + fused alpha dots
#pragma unroll
    for (int rt = 0; rt < 2; ++rt) {
#pragma unroll
        for (int ct = 0; ct < 8; ++ct) {
            int c = ct * 16 + (lane & 15);
#pragma unroll
            for (int j = 0; j < 4; ++j) {
                int row = r0 + rt * 16 + (lane >> 4) * 4 + j;
                if (row < N_NODES) Hb[(size_t)row * 128 + c] = f2bf(acc[rt][ct][j]);
            }
        }
#pragma unroll
        for (int j = 0; j < 4; ++j) {
            float ps = 0.f, pd = 0.f;
#pragma unroll
            for (int ct = 0; ct < 8; ++ct) {
                float v = acc[rt][ct][j];
                ps += v * asv[ct];
                pd += v * adv[ct];
            }
#pragma unroll
            for (int off = 8; off; off >>= 1) {
                ps += __shfl_xor(ps, off);
                pd += __shfl_xor(pd, off);
            }
            int row = r0 + rt * 16 + (lane >> 4) * 4 + j;
            if ((lane & 15) == 0 && row < N_NODES) {
                as_[row] = ps;
                ad_[row] = pd;
            }
        }
    }
}

// ---------------- segment softmax + weighted aggregation (one wave per dst node)
__global__ void k_aggregate(const int* __restrict__ row_ptr, const int* __restrict__ col_src,
                            const unsigned short* __restrict__ Hb,
                            const float* __restrict__ as_, const float* __restrict__ ad_,
                            const float* __restrict__ bias, float* __restrict__ Zout,
                            float* __restrict__ ebuf) {
    int node = blockIdx.x * 4 + (threadIdx.x >> 6);
    int lane = threadIdx.x & 63;
    if (node >= N_NODES) return;

    int start = row_ptr[node], end = row_ptr[node + 1];
    int deg = end - start;
    float ad_i = ad_[node];
    float eself = lrelu(as_[node] + ad_i);
    float m = eself;
    float2 acc;
    float2 hi = ldh2(&Hb[(size_t)node * 128 + lane * 2]);

    if (deg <= 128) {
        int s0 = 0, s1 = 0;
        float e0 = -INFINITY, e1 = -INFINITY;
        if (start + lane < end) {
            s0 = col_src[start + lane];
            e0 = lrelu(as_[s0] + ad_i);
            m = fmaxf(m, e0);
        }
        if (start + 64 + lane < end) {
            s1 = col_src[start + 64 + lane];
            e1 = lrelu(as_[s1] + ad_i);
            m = fmaxf(m, e1);
        }
#pragma unroll
        for (int off = 32; off; off >>= 1) m = fmaxf(m, __shfl_xor(m, off));
        float w0 = __expf(e0 - m);
        float w1 = __expf(e1 - m);
        float p = w0 + w1;
#pragma unroll
        for (int off = 32; off; off >>= 1) p += __shfl_xor(p, off);
        float pself = __expf(eself - m);
        float inv_s = 1.f / (p + pself);
        w0 *= inv_s;
        w1 *= inv_s;
        float wself = pself * inv_s;
        acc.x = wself * hi.x;
        acc.y = wself * hi.y;

        int jmax = deg < 64 ? deg : 64;
        int j = 0;
        for (; j + 8 <= jmax; j += 8) {
            float w[8]; int sv[8];
#pragma unroll
            for (int q = 0; q < 8; ++q) {
                w[q] = __shfl(w0, j + q);
                sv[q] = __shfl(s0, j + q);
            }
            float2 h[8];
#pragma unroll
            for (int q = 0; q < 8; ++q) h[q] = ldh2(&Hb[(size_t)sv[q] * 128 + lane * 2]);
#pragma unroll
            for (int q = 0; q < 8; ++q) {
                acc.x += w[q] * h[q].x;
                acc.y += w[q] * h[q].y;
            }
        }
        for (; j < jmax; ++j) {
            float w = __shfl(w0, j);
            int sv = __shfl(s0, j);
            float2 hs = ldh2(&Hb[(size_t)sv * 128 + lane * 2]);
            acc.x += w * hs.x;
            acc.y += w * hs.y;
        }
        for (j = 64; j < deg; ++j) {
            float w = __shfl(w1, j - 64);
            int sv = __shfl(s1, j - 64);
            float2 hs = ldh2(&Hb[(size_t)sv * 128 + lane * 2]);
            acc.x += w * hs.x;
            acc.y += w * hs.y;
        }
    } else {
        for (int j = start + lane; j < end; j += 64) {
            int sj = col_src[j];
            float e = lrelu(as_[sj] + ad_i);
            ebuf[j] = e;
            m = fmaxf(m, e);
        }
#pragma unroll
        for (int off = 32; off; off >>= 1) m = fmaxf(m, __shfl_xor(m, off));
        float p = 0.f;
        for (int j = start + lane; j < end; j += 64) p += __expf(ebuf[j] - m);
#pragma unroll
        for (int off = 32; off; off >>= 1) p += __shfl_xor(p, off);
        float pself = __expf(eself - m);
        float inv_s = 1.f / (p + pself);
        float wself = pself * inv_s;
        acc.x = wself * hi.x;
        acc.y = wself * hi.y;
        for (int j = start; j < end; ++j) {
            int sv = col_src[j];
            float w = __expf(ebuf[j] - m) * inv_s;
            float2 hs = ldh2(&Hb[(size_t)sv * 128 + lane * 2]);
            acc.x += w * hs.x;
            acc.y += w * hs.y;
        }
    }

    float2 bv = *(const float2*)&bias[lane * 2];
    float2 o;
    o.x = acc.x + bv.x;
    o.y = acc.y + bv.y;
    *(float2*)&Zout[(size_t)node * 128 + lane * 2] = o;
}

// ---------------- BatchNorm stats (training, biased var)
__global__ void k_bnstats(const float* __restrict__ Z, float* __restrict__ part) {
    int c = threadIdx.x;
    float s = 0.f, sq = 0.f;
    for (int i = blockIdx.x; i < N_NODES; i += gridDim.x) {
        float v = Z[(size_t)i * 128 + c];
        s += v;
        sq += v * v;
    }
    part[blockIdx.x * 256 + c] = s;
    part[blockIdx.x * 256 + 128 + c] = sq;
}

__global__ void k_bnfinal(const float* __restrict__ part, float* __restrict__ mu,
                          float* __restrict__ rs) {
    int c = threadIdx.x;
    float s = 0.f, sq = 0.f;
    for (int b = 0; b < 512; ++b) {
        s += part[b * 256 + c];
        sq += part[b * 256 + 128 + c];
    }
    float m = s / (float)N_NODES;
    float var = sq / (float)N_NODES - m * m;
    mu[c] = m;
    rs[c] = rsqrtf(var + EPS);
}

// final-layer BN+ReLU apply -> fp32 out
__global__ void k_bnapply(const float* __restrict__ Zin, const float* __restrict__ mu,
                          const float* __restrict__ rs, float* __restrict__ Zout) {
    int idx = blockIdx.x * blockDim.x + threadIdx.x;
    if (idx >= N_NODES * 32) return;
    int c4 = idx & 31;
    float4 v = ((const float4*)Zin)[idx];
    float4 m4 = ((const float4*)mu)[c4];
    float4 r4 = ((const float4*)rs)[c4];
    v.x = fmaxf((v.x - m4.x) * r4.x, 0.f);
    v.y = fmaxf((v.y - m4.y) * r4.y, 0.f);
    v.z = fmaxf((v.z - m4.z) * r4.z, 0.f);
    v.w = fmaxf((v.w - m4.w) * r4.w, 0.f);
    ((float4*)Zout)[idx] = v;
}

extern "C" void kernel_launch(void* const* d_in, const int* in_sizes, int n_in,
                              void* d_out, int out_size, void* d_ws, size_t ws_size,
                              hipStream_t stream) {
    const float* x = (const float*)d_in[0];
    const int* ei = (const int*)d_in[1];
    const int* srcp = ei;
    const int* dstp = ei + N_EDGES;
    const float* W = (const float*)d_in[2];
    const float* a_src = (const float*)d_in[3];
    const float* a_dst = (const float*)d_in[4];
    const float* bias = (const float*)d_in[5];
    float* out = (float*)d_out;

    char* ws = (char*)d_ws;
    size_t off = 0;
    auto alloc = [&](size_t bytes) -> void* {
        void* p = ws + off;
        off = (off + bytes + 255) & ~(size_t)255;
        return p;
    };
    int* bcnt     = (int*)alloc(NBUCK * 4);
    int* bbase    = (int*)alloc((NBUCK + 1) * 4);
    int* gtail    = (int*)alloc(NBUCK * 4);
    int* row_ptr  = (int*)alloc((N_NODES + 1) * 4);
    int* col_src  = (int*)alloc(N_EDGES * 4);
    uint2* staged = (uint2*)alloc((size_t)N_EDGES * 8);   // aliased by ebuf later
    unsigned short* hbf = (unsigned short*)alloc((size_t)N_NODES * DIM * 2);
    float* zbuf   = (float*)alloc((size_t)N_NODES * DIM * 4);
    unsigned short* wtb = (unsigned short*)alloc(3 * 16384 * 2);
    float* asb    = (float*)alloc(N_NODES * 4);
    float* adb    = (float*)alloc(N_NODES * 4);
    float* part   = (float*)alloc(512 * 256 * 4);
    float* mu     = (float*)alloc(128 * 4);
    float* rsg    = (float*)alloc(128 * 4);
    if (off > ws_size) return;

    float* ebuf = (float*)staged;   // aggregate-only scratch (after partC done)

    hipMemsetAsync(bcnt, 0, NBUCK * 4, stream);
    k_hist<<<256, 256, 0, stream>>>(dstp, bcnt);
    k_bscan<<<1, NBUCK, 0, stream>>>(bcnt, bbase, gtail);
    k_partB<<<NBLK_B, 256, 0, stream>>>(srcp, dstp, gtail, staged);
    k_partC<<<NBUCK, 256, 0, stream>>>(staged, bbase, row_ptr, col_src);
    k_prepW<<<192, 256, 0, stream>>>(W, wtb);

    const float* zin = x;
    for (int l = 0; l < 3; ++l) {
        k_gemm_mfma<<<(N_NODES + 127) / 128, 256, 0, stream>>>(
            zin, wtb + l * 16384, hbf, (l == 0) ? nullptr : mu, rsg,
            a_src + l * DIM, a_dst + l * DIM, asb, adb);
        k_aggregate<<<(N_NODES + 3) / 4, 256, 0, stream>>>(row_ptr, col_src, hbf, asb, adb,
                                                           bias + l * DIM, zbuf, ebuf);
        k_bnstats<<<512, 128, 0, stream>>>(zbuf, part);
        k_bnfinal<<<1, 128, 0, stream>>>(part, mu, rsg);
        if (l == 2)
            k_bnapply<<<(N_NODES * 32 + 255) / 256, 256, 0, stream>>>(zbuf, mu, rsg, out);
        zin = zbuf;
    }
}